// Round 10
// baseline (420.423 us; speedup 1.0000x reference)
//
#include <hip/hip_runtime.h>
#include <cstdint>
#include <cstddef>

#define NHEAD 4
#define HID 64
#define NCOL 256          // NHEAD*HID
#define INDIM 128
#define PREDDIM 16
#define RELNUM 50
#define NLAYER 3
#define ECHUNK 8192       // edges per chunk-block in bucket build
#define DSHIFT 9          // 512 dsts per bucket
#define DPB 512           // dsts per bucket (src17+type6+dstLow9 = 32 bits)
#define MAXBUCK 256       // >= ceil(N/DPB)=196; LDS hist size
#define MLP_NODES 64      // nodes per block in MFMA MLP

typedef _Float16 half8 __attribute__((ext_vector_type(8)));
typedef float float4v __attribute__((ext_vector_type(4)));

// ---------------- W1 hi/lo f16 split (once) ----------------
// fp32 = hi + lo/2048 exactly to ~2^-22 rel; lo scaled x2048 so W~0.05
// residuals stay in f16 normal range (avoids denorm-flush error).
__global__ void split_w1(const float* __restrict__ W1,
                         _Float16* __restrict__ Wh, _Float16* __restrict__ Wl)
{
    int i = blockIdx.x * 256 + threadIdx.x;    // NCOL*INDIM = 32768 total
    float v = W1[i];
    _Float16 h = (_Float16)v;
    Wh[i] = h;
    Wl[i] = (_Float16)((v - (float)h) * 2048.0f);
}

// ---------------- node scoring MLP via split-f16 MFMA ----------------
// Round-7 lesson: full ct-unroll hoisted 128 VGPRs of B-frags -> spill ->
// 150 MB scratch writes. ct loop stays '#pragma unroll 1'.
// Fragment conventions (verified rounds 5-9 passing): A[m=lane&15]
// [k=(lane>>4)*8+j], B[n=lane&15][k=(lane>>4)*8+j], D col=lane&15 (B n),
// row=(lane>>4)*4+reg (A m).
__global__ __launch_bounds__(256, 2) void mlp_mfma_kernel(
    const float* __restrict__ X, const _Float16* __restrict__ Wh,
    const _Float16* __restrict__ Wl, const float* __restrict__ b1,
    const float* __restrict__ W2, const float* __restrict__ b2,
    float* __restrict__ h0, int N)
{
    __shared__ _Float16 hA[4][4][64][8];   // [mt][ks][lane][j], 16 KB
    __shared__ _Float16 lA[4][4][64][8];

    const int tid = threadIdx.x;
    const int n0  = blockIdx.x * MLP_NODES;

    // ---- stage: thread = (node mg=tid>>2, ks=tid&3): 32 floats -> hi/lo ----
    {
        const int mg = tid >> 2, ks = tid & 3;
        const int gn = min(n0 + mg, N - 1);     // clamp; stores guarded later
        const float4* Xp = reinterpret_cast<const float4*>(X + (size_t)gn * INDIM + ks * 32);
        const int mt = mg >> 4, m = mg & 15;
        #pragma unroll
        for (int q = 0; q < 4; q++) {
            float4 x0 = Xp[q * 2], x1 = Xp[q * 2 + 1];
            float xs[8] = { x0.x,x0.y,x0.z,x0.w, x1.x,x1.y,x1.z,x1.w };
            half8 hv, lv;
            #pragma unroll
            for (int j = 0; j < 8; j++) {
                _Float16 hh = (_Float16)xs[j];
                hv[j] = hh;
                lv[j] = (_Float16)((xs[j] - (float)hh) * 2048.0f);
            }
            *reinterpret_cast<half8*>(&hA[mt][ks][q * 16 + m][0]) = hv;
            *reinterpret_cast<half8*>(&lA[mt][ks][q * 16 + m][0]) = lv;
        }
    }
    __syncthreads();

    const int w    = tid >> 6;             // wave = head
    const int lane = tid & 63;
    const int n16  = lane & 15;
    const int q    = lane >> 4;

    float s[4][4];                         // [mt][reg] per-head partials
    #pragma unroll
    for (int mt = 0; mt < 4; mt++)
        #pragma unroll
        for (int r = 0; r < 4; r++) s[mt][r] = 0.f;

    #pragma unroll 1                       // DO NOT unroll: keeps one ct's
    for (int ct = 0; ct < 4; ct++) {       // B-frags (32 VGPR) live, not 128
        const int c = w * 64 + ct * 16 + n16;
        const _Float16* pb = Wh + (size_t)c * INDIM + q * 8;
        const _Float16* pl = Wl + (size_t)c * INDIM + q * 8;
        half8 bh[4], bl[4];
        #pragma unroll
        for (int ks = 0; ks < 4; ks++) {
            bh[ks] = *reinterpret_cast<const half8*>(pb + ks * 32);
            bl[ks] = *reinterpret_cast<const half8*>(pl + ks * 32);
        }
        const float b1v = b1[c];
        const float w2v = W2[c];

        #pragma unroll
        for (int mt = 0; mt < 4; mt++) {
            float4v acc = (float4v){0.f,0.f,0.f,0.f};
            float4v aca = (float4v){0.f,0.f,0.f,0.f};
            float4v acb = (float4v){0.f,0.f,0.f,0.f};
            #pragma unroll
            for (int ks = 0; ks < 4; ks++) {
                half8 ah = *reinterpret_cast<const half8*>(&hA[mt][ks][lane][0]);
                half8 al = *reinterpret_cast<const half8*>(&lA[mt][ks][lane][0]);
                acc = __builtin_amdgcn_mfma_f32_16x16x32_f16(ah, bh[ks], acc, 0, 0, 0);
                aca = __builtin_amdgcn_mfma_f32_16x16x32_f16(ah, bl[ks], aca, 0, 0, 0);
                acb = __builtin_amdgcn_mfma_f32_16x16x32_f16(al, bh[ks], acb, 0, 0, 0);
            }
            #pragma unroll
            for (int r = 0; r < 4; r++) {
                float v = acc[r] + (aca[r] + acb[r]) * (1.0f / 2048.0f) + b1v;
                s[mt][r] += fmaxf(v, 0.f) * w2v;
            }
        }
    }

    // ---- reduce over n16 (16 lanes = 16 cols of this head) + store ----
    const float bk = b2[w];
    #pragma unroll
    for (int mt = 0; mt < 4; mt++) {
        #pragma unroll
        for (int r = 0; r < 4; r++) {
            float v = s[mt][r];
            v += __shfl_down(v, 8, 16);
            v += __shfl_down(v, 4, 16);
            v += __shfl_down(v, 2, 16);
            v += __shfl_down(v, 1, 16);
            if (n16 == 0) {
                int node = n0 + mt * 16 + q * 4 + r;
                if (node < N) h0[(size_t)node * NHEAD + w] = v + bk;
            }
        }
    }
}

// ---------------- attention weight table ----------------
__global__ void table_kernel(const float* __restrict__ rel_emb,
                             const float* __restrict__ W_pred,
                             float* __restrict__ wtab)
{
    int idx = blockIdx.x * blockDim.x + threadIdx.x;
    if (idx >= NLAYER * RELNUM * NHEAD) return;
    int h = idx & 3;
    int q = idx >> 2;
    int t = q % RELNUM;
    int l = q / RELNUM;
    float acc = 0.f;
    #pragma unroll
    for (int p = 0; p < PREDDIM; p++)
        acc = fmaf(rel_emb[t * PREDDIM + p], W_pred[l * PREDDIM * NHEAD + p * NHEAD + h], acc);
    float e = (acc >= 0.f) ? acc : 0.2f * acc;
    wtab[idx] = __expf(e);
}

// ---------------- bucketed CSR build ----------------
// Round-9: scatter was latency-bound (196 blocks x 4 waves, occupancy 6%,
// two full dst passes). Now: count writes per-chunk hist rows; scan
// precomputes per-(chunk,bucket) bases; scatter is ONE pass with 1024-thread
// blocks (391 x 16 waves) and int4 edge loads.
__global__ __launch_bounds__(1024) void bucket_count_kernel(
    const int* __restrict__ dst, int* __restrict__ blockhist, int E, int nbuck)
{
    __shared__ int hist[MAXBUCK];
    const int tid = threadIdx.x;
    if (tid < MAXBUCK) hist[tid] = 0;
    __syncthreads();
    const int base = blockIdx.x * ECHUNK;
    const int end  = min(base + ECHUNK, E);
    const int nvec = (end - base) >> 2;
    const int4* d4p = reinterpret_cast<const int4*>(dst + base);
    for (int g = tid; g < nvec; g += 1024) {
        int4 d = d4p[g];
        atomicAdd(&hist[d.x >> DSHIFT], 1);
        atomicAdd(&hist[d.y >> DSHIFT], 1);
        atomicAdd(&hist[d.z >> DSHIFT], 1);
        atomicAdd(&hist[d.w >> DSHIFT], 1);
    }
    for (int i = base + (nvec << 2) + tid; i < end; i += 1024)
        atomicAdd(&hist[dst[i] >> DSHIFT], 1);
    __syncthreads();
    if (tid < nbuck) blockhist[(size_t)blockIdx.x * nbuck + tid] = hist[tid];
}

// one block: bucket totals, CSR bucket starts, per-(chunk,bucket) bases.
// lane t <-> bucket t: blockhist[k*nbuck+t] accesses are lane-coalesced.
__global__ __launch_bounds__(256) void scan_buckets_kernel(
    const int* __restrict__ blockhist, int* __restrict__ bucket_start,
    int* __restrict__ bucket_size, int* __restrict__ blockbase,
    int nbuck, int nb)
{
    __shared__ int s[256];
    const int t = threadIdx.x;
    int tot = 0;
    if (t < nbuck)
        for (int k = 0; k < nb; k++) tot += blockhist[(size_t)k * nbuck + t];
    s[t] = (t < nbuck) ? tot : 0;
    __syncthreads();
    for (int off = 1; off < 256; off <<= 1) {
        int u = (t >= off) ? s[t - off] : 0;
        __syncthreads();
        s[t] += u;
        __syncthreads();
    }
    if (t < nbuck) {
        int ex = s[t] - tot;
        bucket_start[t] = ex;
        bucket_size[t]  = tot;
        int run = ex;
        for (int k = 0; k < nb; k++) {
            blockbase[(size_t)k * nbuck + t] = run;
            run += blockhist[(size_t)k * nbuck + t];
        }
    }
}

__global__ __launch_bounds__(1024) void bucket_scatter_kernel(
    const int* __restrict__ src, const int* __restrict__ dst,
    const int* __restrict__ types, const int* __restrict__ blockbase,
    int* __restrict__ bucketed, int E, int nbuck)
{
    __shared__ int lbase[MAXBUCK];
    __shared__ int cur[MAXBUCK];
    const int tid = threadIdx.x;
    if (tid < MAXBUCK) {
        lbase[tid] = (tid < nbuck) ? blockbase[(size_t)blockIdx.x * nbuck + tid] : 0;
        cur[tid] = 0;
    }
    __syncthreads();
    const int base = blockIdx.x * ECHUNK;
    const int end  = min(base + ECHUNK, E);
    const int nvec = (end - base) >> 2;
    const int4* s4p = reinterpret_cast<const int4*>(src + base);
    const int4* d4p = reinterpret_cast<const int4*>(dst + base);
    const int4* t4p = reinterpret_cast<const int4*>(types + base);
    for (int g = tid; g < nvec; g += 1024) {
        int4 sv = s4p[g], dv = d4p[g], tv = t4p[g];
        int b, r;
        // src(0..16) | type(17..22) | dstLow(23..31) - sign bit ok, masked on use
        b = dv.x >> DSHIFT; r = atomicAdd(&cur[b], 1);
        bucketed[lbase[b] + r] = sv.x | (tv.x << 17) | ((dv.x & (DPB - 1)) << 23);
        b = dv.y >> DSHIFT; r = atomicAdd(&cur[b], 1);
        bucketed[lbase[b] + r] = sv.y | (tv.y << 17) | ((dv.y & (DPB - 1)) << 23);
        b = dv.z >> DSHIFT; r = atomicAdd(&cur[b], 1);
        bucketed[lbase[b] + r] = sv.z | (tv.z << 17) | ((dv.z & (DPB - 1)) << 23);
        b = dv.w >> DSHIFT; r = atomicAdd(&cur[b], 1);
        bucketed[lbase[b] + r] = sv.w | (tv.w << 17) | ((dv.w & (DPB - 1)) << 23);
    }
    for (int i = base + (nvec << 2) + tid; i < end; i += 1024) {
        int d = dst[i];
        int b = d >> DSHIFT;
        int r = atomicAdd(&cur[b], 1);
        bucketed[lbase[b] + r] = src[i] | (types[i] << 17) | ((d & (DPB - 1)) << 23);
    }
}

// 1024 threads; scan section runs on first DPB=512 threads.
__global__ __launch_bounds__(1024) void bucket_to_csr_kernel(
    const int* __restrict__ bucket_start, const int* __restrict__ bucket_size,
    const int* __restrict__ bucketed, int* __restrict__ sorted,
    int* __restrict__ row_start, int* __restrict__ deg, int N)
{
    __shared__ int cnt[DPB];
    __shared__ int sc[DPB];
    __shared__ int rs[DPB];
    __shared__ int cur[DPB];
    const int tid = threadIdx.x;
    const int b   = blockIdx.x;
    const int d0  = b << DSHIFT;
    const int nd  = min(DPB, N - d0);
    const int s0  = bucket_start[b];
    const int ne  = bucket_size[b];

    if (tid < DPB) { cnt[tid] = 0; cur[tid] = 0; }
    __syncthreads();
    for (int i = tid; i < ne; i += 1024)
        atomicAdd(&cnt[((unsigned)bucketed[s0 + i] >> 23) & (DPB - 1)], 1);
    __syncthreads();
    int v = 0;
    if (tid < DPB) { v = cnt[tid]; sc[tid] = v; }
    __syncthreads();
    for (int off = 1; off < DPB; off <<= 1) {
        int u = (tid < DPB && tid >= off) ? sc[tid - off] : 0;
        __syncthreads();
        if (tid < DPB) sc[tid] += u;
        __syncthreads();
    }
    if (tid < DPB) {
        int ex = sc[tid] - v;
        rs[tid] = s0 + ex;
        if (tid < nd) {
            row_start[d0 + tid] = s0 + ex;
            deg[d0 + tid] = v;
        }
    }
    __syncthreads();
    for (int i = tid; i < ne; i += 1024) {
        int pk = bucketed[s0 + i];
        int d  = ((unsigned)pk >> 23) & (DPB - 1);
        int r  = atomicAdd(&cur[d], 1);
        sorted[rs[d] + r] = pk & 0x7FFFFF;   // src | type<<17
    }
}

// ---------------- per-layer aggregation ----------------
template <int MODE>
__global__ __launch_bounds__(256) void agg_kernel(
    const int* __restrict__ row_start, const int* __restrict__ deg,
    const int* __restrict__ sorted, const float* __restrict__ wt_l,
    const float* __restrict__ hin, float* __restrict__ hout,
    const float* __restrict__ centrality, const float* __restrict__ gamma,
    const float* __restrict__ beta, int N)
{
    __shared__ float wt[RELNUM * NHEAD];
    for (int i = threadIdx.x; i < RELNUM * NHEAD; i += blockDim.x) wt[i] = wt_l[i];
    __syncthreads();

    int gid = blockIdx.x * blockDim.x + threadIdx.x;
    int d = gid >> 2, h = gid & 3;
    if (d >= N) return;

    int b = row_start[d], n = deg[d];
    float num = 0.f, den = 0.f;
    for (int i = 0; i < n; i++) {
        int pk = sorted[b + i];                 // same addr across the quad
        int s = pk & 0x1FFFF;
        int t = pk >> 17;
        float wv = wt[t * NHEAD + h];
        float hv = (MODE == 0) ? hin[(size_t)s * NHEAD + h] : hin[s];
        num = fmaf(wv, hv, num);
        den += wv;
    }
    float r = (n > 0) ? fmaxf(num / den, 0.f) : 0.f;   // relu(segsum(a*h))
    if (MODE == 2) r = (centrality[d] * gamma[h] + beta[h]) * r;
    r += __shfl_xor(r, 1);
    r += __shfl_xor(r, 2);
    r *= 0.25f;
    if (h == 0) {
        if (MODE < 2) hout[d] = r;
        else          hout[d] = (r > 0.f) ? r : 0.01f * r;
    }
}

// ---------------- launch ----------------
extern "C" void kernel_launch(void* const* d_in, const int* in_sizes, int n_in,
                              void* d_out, int out_size, void* d_ws, size_t ws_size,
                              hipStream_t stream)
{
    const float* X          = (const float*)d_in[0];
    const float* centrality = (const float*)d_in[1];
    const float* W1         = (const float*)d_in[2];
    const float* b1         = (const float*)d_in[3];
    const float* W2         = (const float*)d_in[4];
    const float* b2         = (const float*)d_in[5];
    const float* rel_emb    = (const float*)d_in[6];
    const float* W_pred     = (const float*)d_in[7];
    const float* gamma      = (const float*)d_in[8];
    const float* beta       = (const float*)d_in[9];
    const int*   edge_types = (const int*)d_in[10];
    const int*   src        = (const int*)d_in[11];
    const int*   dst        = (const int*)d_in[12];
    float* out = (float*)d_out;

    const int N = in_sizes[1];
    const int E = in_sizes[10];
    const int nbuck = (N + DPB - 1) / DPB;
    const int eb = (E + ECHUNK - 1) / ECHUNK;

    char* ws = (char*)d_ws;
    size_t off = 0;
    auto alloc = [&](size_t bytes) -> void* {
        void* p = ws + off;
        off = (off + bytes + 255) & ~(size_t)255;
        return p;
    };
    int*   deg       = (int*)alloc((size_t)N * 4);
    int*   row_start = (int*)alloc((size_t)N * 4);
    int*   bsize     = (int*)alloc((size_t)MAXBUCK * 4);
    int*   bstart    = (int*)alloc((size_t)MAXBUCK * 4);
    int*   blockhist = (int*)alloc((size_t)eb * nbuck * 4);
    int*   blockbase = (int*)alloc((size_t)eb * nbuck * 4);
    int*   bucketed  = (int*)alloc((size_t)E * 4);
    int*   sorted    = (int*)alloc((size_t)E * 4);
    float* wtab      = (float*)alloc((size_t)NLAYER * RELNUM * NHEAD * 4);
    float* h0        = (float*)alloc((size_t)N * NHEAD * 4);
    float* hs        = (float*)alloc((size_t)N * 4);
    float* hs2       = (float*)alloc((size_t)N * 4);
    _Float16* Wh     = (_Float16*)alloc((size_t)NCOL * INDIM * 2);
    _Float16* Wl     = (_Float16*)alloc((size_t)NCOL * INDIM * 2);
    (void)ws_size; (void)n_in; (void)out_size;

    bucket_count_kernel<<<eb, 1024, 0, stream>>>(dst, blockhist, E, nbuck);
    scan_buckets_kernel<<<1, 256, 0, stream>>>(blockhist, bstart, bsize,
                                               blockbase, nbuck, eb);
    bucket_scatter_kernel<<<eb, 1024, 0, stream>>>(src, dst, edge_types, blockbase,
                                                   bucketed, E, nbuck);
    bucket_to_csr_kernel<<<nbuck, 1024, 0, stream>>>(bstart, bsize, bucketed, sorted,
                                                     row_start, deg, N);

    table_kernel<<<(NLAYER * RELNUM * NHEAD + 255) / 256, 256, 0, stream>>>(rel_emb, W_pred, wtab);
    split_w1<<<(NCOL * INDIM) / 256, 256, 0, stream>>>(W1, Wh, Wl);
    mlp_mfma_kernel<<<(N + MLP_NODES - 1) / MLP_NODES, 256, 0, stream>>>(
        X, Wh, Wl, b1, W2, b2, h0, N);

    const int ab = (N * NHEAD + 255) / 256;
    agg_kernel<0><<<ab, 256, 0, stream>>>(row_start, deg, sorted, wtab + 0 * RELNUM * NHEAD,
                                          h0, hs, nullptr, nullptr, nullptr, N);
    agg_kernel<1><<<ab, 256, 0, stream>>>(row_start, deg, sorted, wtab + 1 * RELNUM * NHEAD,
                                          hs, hs2, nullptr, nullptr, nullptr, N);
    agg_kernel<2><<<ab, 256, 0, stream>>>(row_start, deg, sorted, wtab + 2 * RELNUM * NHEAD,
                                          hs2, out, centrality, gamma, beta, N);
}

// Round 11
// 294.914 us; speedup vs baseline: 1.4256x; 1.4256x over previous
//
#include <hip/hip_runtime.h>
#include <cstdint>
#include <cstddef>

#define NHEAD 4
#define HID 64
#define NCOL 256          // NHEAD*HID
#define INDIM 128
#define PREDDIM 16
#define RELNUM 50
#define NLAYER 3
#define ECHUNK 8192       // edges per chunk-block in bucket build
#define DSHIFT 9          // 512 dsts per bucket
#define DPB 512           // dsts per bucket (src17+type6+dstLow9 = 32 bits)
#define MAXBUCK 256       // >= ceil(N/DPB)=196; LDS hist size
#define MAXCHUNK 512      // >= ceil(E/ECHUNK)=391
#define MLP_NODES 64      // nodes per block in MFMA MLP

typedef _Float16 half8 __attribute__((ext_vector_type(8)));
typedef float float4v __attribute__((ext_vector_type(4)));

// ---------------- W1 hi/lo f16 split (once) ----------------
// fp32 = hi + lo/2048 exactly to ~2^-22 rel; lo scaled x2048 so W~0.05
// residuals stay in f16 normal range (avoids denorm-flush error).
__global__ void split_w1(const float* __restrict__ W1,
                         _Float16* __restrict__ Wh, _Float16* __restrict__ Wl)
{
    int i = blockIdx.x * 256 + threadIdx.x;    // NCOL*INDIM = 32768 total
    float v = W1[i];
    _Float16 h = (_Float16)v;
    Wh[i] = h;
    Wl[i] = (_Float16)((v - (float)h) * 2048.0f);
}

// ---------------- node scoring MLP via split-f16 MFMA ----------------
// Round-7 lesson: full ct-unroll hoisted 128 VGPRs of B-frags -> spill ->
// 150 MB scratch writes. ct loop stays '#pragma unroll 1'.
// Fragment conventions (verified rounds 5-10 passing): A[m=lane&15]
// [k=(lane>>4)*8+j], B[n=lane&15][k=(lane>>4)*8+j], D col=lane&15 (B n),
// row=(lane>>4)*4+reg (A m).
__global__ __launch_bounds__(256, 2) void mlp_mfma_kernel(
    const float* __restrict__ X, const _Float16* __restrict__ Wh,
    const _Float16* __restrict__ Wl, const float* __restrict__ b1,
    const float* __restrict__ W2, const float* __restrict__ b2,
    float* __restrict__ h0, int N)
{
    __shared__ _Float16 hA[4][4][64][8];   // [mt][ks][lane][j], 16 KB
    __shared__ _Float16 lA[4][4][64][8];

    const int tid = threadIdx.x;
    const int n0  = blockIdx.x * MLP_NODES;

    // ---- stage: thread = (node mg=tid>>2, ks=tid&3): 32 floats -> hi/lo ----
    {
        const int mg = tid >> 2, ks = tid & 3;
        const int gn = min(n0 + mg, N - 1);     // clamp; stores guarded later
        const float4* Xp = reinterpret_cast<const float4*>(X + (size_t)gn * INDIM + ks * 32);
        const int mt = mg >> 4, m = mg & 15;
        #pragma unroll
        for (int q = 0; q < 4; q++) {
            float4 x0 = Xp[q * 2], x1 = Xp[q * 2 + 1];
            float xs[8] = { x0.x,x0.y,x0.z,x0.w, x1.x,x1.y,x1.z,x1.w };
            half8 hv, lv;
            #pragma unroll
            for (int j = 0; j < 8; j++) {
                _Float16 hh = (_Float16)xs[j];
                hv[j] = hh;
                lv[j] = (_Float16)((xs[j] - (float)hh) * 2048.0f);
            }
            *reinterpret_cast<half8*>(&hA[mt][ks][q * 16 + m][0]) = hv;
            *reinterpret_cast<half8*>(&lA[mt][ks][q * 16 + m][0]) = lv;
        }
    }
    __syncthreads();

    const int w    = tid >> 6;             // wave = head
    const int lane = tid & 63;
    const int n16  = lane & 15;
    const int q    = lane >> 4;

    float s[4][4];                         // [mt][reg] per-head partials
    #pragma unroll
    for (int mt = 0; mt < 4; mt++)
        #pragma unroll
        for (int r = 0; r < 4; r++) s[mt][r] = 0.f;

    #pragma unroll 1                       // DO NOT unroll: keeps one ct's
    for (int ct = 0; ct < 4; ct++) {       // B-frags (32 VGPR) live, not 128
        const int c = w * 64 + ct * 16 + n16;
        const _Float16* pb = Wh + (size_t)c * INDIM + q * 8;
        const _Float16* pl = Wl + (size_t)c * INDIM + q * 8;
        half8 bh[4], bl[4];
        #pragma unroll
        for (int ks = 0; ks < 4; ks++) {
            bh[ks] = *reinterpret_cast<const half8*>(pb + ks * 32);
            bl[ks] = *reinterpret_cast<const half8*>(pl + ks * 32);
        }
        const float b1v = b1[c];
        const float w2v = W2[c];

        #pragma unroll
        for (int mt = 0; mt < 4; mt++) {
            float4v acc = (float4v){0.f,0.f,0.f,0.f};
            float4v aca = (float4v){0.f,0.f,0.f,0.f};
            float4v acb = (float4v){0.f,0.f,0.f,0.f};
            #pragma unroll
            for (int ks = 0; ks < 4; ks++) {
                half8 ah = *reinterpret_cast<const half8*>(&hA[mt][ks][lane][0]);
                half8 al = *reinterpret_cast<const half8*>(&lA[mt][ks][lane][0]);
                acc = __builtin_amdgcn_mfma_f32_16x16x32_f16(ah, bh[ks], acc, 0, 0, 0);
                aca = __builtin_amdgcn_mfma_f32_16x16x32_f16(ah, bl[ks], aca, 0, 0, 0);
                acb = __builtin_amdgcn_mfma_f32_16x16x32_f16(al, bh[ks], acb, 0, 0, 0);
            }
            #pragma unroll
            for (int r = 0; r < 4; r++) {
                float v = acc[r] + (aca[r] + acb[r]) * (1.0f / 2048.0f) + b1v;
                s[mt][r] += fmaxf(v, 0.f) * w2v;
            }
        }
    }

    // ---- reduce over n16 (16 lanes = 16 cols of this head) + store ----
    const float bk = b2[w];
    #pragma unroll
    for (int mt = 0; mt < 4; mt++) {
        #pragma unroll
        for (int r = 0; r < 4; r++) {
            float v = s[mt][r];
            v += __shfl_down(v, 8, 16);
            v += __shfl_down(v, 4, 16);
            v += __shfl_down(v, 2, 16);
            v += __shfl_down(v, 1, 16);
            if (n16 == 0) {
                int node = n0 + mt * 16 + q * 4 + r;
                if (node < N) h0[(size_t)node * NHEAD + w] = v + bk;
            }
        }
    }
}

// ---------------- attention weight table ----------------
__global__ void table_kernel(const float* __restrict__ rel_emb,
                             const float* __restrict__ W_pred,
                             float* __restrict__ wtab)
{
    int idx = blockIdx.x * blockDim.x + threadIdx.x;
    if (idx >= NLAYER * RELNUM * NHEAD) return;
    int h = idx & 3;
    int q = idx >> 2;
    int t = q % RELNUM;
    int l = q / RELNUM;
    float acc = 0.f;
    #pragma unroll
    for (int p = 0; p < PREDDIM; p++)
        acc = fmaf(rel_emb[t * PREDDIM + p], W_pred[l * PREDDIM * NHEAD + p * NHEAD + h], acc);
    float e = (acc >= 0.f) ? acc : 0.2f * acc;
    wtab[idx] = __expf(e);
}

// ---------------- bucketed CSR build ----------------
// Round-10 failure: scan_buckets computed per-(chunk,bucket) bases with a
// SERIAL loop over 391 chunks in one 256-thread block -> 135 us. Fix:
// per-bucket parallel chunk-scan kernel (196 blocks x 512 thr, LDS
// Hillis-Steele); tiny 196-wide bucket scan stays single-block.
// blockhist/blockbase are BUCKET-MAJOR: [bucket][chunk].
__global__ __launch_bounds__(1024) void bucket_count_kernel(
    const int* __restrict__ dst, int* __restrict__ blockhist, int E,
    int nbuck, int nb)
{
    __shared__ int hist[MAXBUCK];
    const int tid = threadIdx.x;
    if (tid < MAXBUCK) hist[tid] = 0;
    __syncthreads();
    const int base = blockIdx.x * ECHUNK;
    const int end  = min(base + ECHUNK, E);
    const int nvec = (end - base) >> 2;
    const int4* d4p = reinterpret_cast<const int4*>(dst + base);
    for (int g = tid; g < nvec; g += 1024) {
        int4 d = d4p[g];
        atomicAdd(&hist[d.x >> DSHIFT], 1);
        atomicAdd(&hist[d.y >> DSHIFT], 1);
        atomicAdd(&hist[d.z >> DSHIFT], 1);
        atomicAdd(&hist[d.w >> DSHIFT], 1);
    }
    for (int i = base + (nvec << 2) + tid; i < end; i += 1024)
        atomicAdd(&hist[dst[i] >> DSHIFT], 1);
    __syncthreads();
    if (tid < nbuck) blockhist[(size_t)tid * nb + blockIdx.x] = hist[tid];
}

// one block per bucket: exclusive scan over its nb chunk counts (nb<=512)
__global__ __launch_bounds__(512) void scan_chunks_kernel(
    const int* __restrict__ blockhist, int* __restrict__ blockbase,
    int* __restrict__ bucket_size, int nb)
{
    __shared__ int s[MAXCHUNK];
    const int b = blockIdx.x;
    const int t = threadIdx.x;
    int v = (t < nb) ? blockhist[(size_t)b * nb + t] : 0;
    s[t] = v;
    __syncthreads();
    for (int off = 1; off < MAXCHUNK; off <<= 1) {
        int u = (t >= off) ? s[t - off] : 0;
        __syncthreads();
        s[t] += u;
        __syncthreads();
    }
    if (t < nb) blockbase[(size_t)b * nb + t] = s[t] - v;   // excl. within bucket
    if (t == MAXCHUNK - 1) bucket_size[b] = s[t];
}

// one small block: exclusive scan of bucket sizes (nbuck <= 256)
__global__ __launch_bounds__(256) void scan_buckets_kernel(
    const int* __restrict__ bucket_size, int* __restrict__ bucket_start, int nbuck)
{
    __shared__ int s[256];
    const int t = threadIdx.x;
    int v = (t < nbuck) ? bucket_size[t] : 0;
    s[t] = v;
    __syncthreads();
    for (int off = 1; off < 256; off <<= 1) {
        int u = (t >= off) ? s[t - off] : 0;
        __syncthreads();
        s[t] += u;
        __syncthreads();
    }
    if (t < nbuck) bucket_start[t] = s[t] - v;
}

__global__ __launch_bounds__(1024) void bucket_scatter_kernel(
    const int* __restrict__ src, const int* __restrict__ dst,
    const int* __restrict__ types, const int* __restrict__ blockbase,
    const int* __restrict__ bucket_start, int* __restrict__ bucketed,
    int E, int nbuck, int nb)
{
    __shared__ int lbase[MAXBUCK];
    __shared__ int cur[MAXBUCK];
    const int tid = threadIdx.x;
    if (tid < MAXBUCK) {
        lbase[tid] = (tid < nbuck)
            ? blockbase[(size_t)tid * nb + blockIdx.x] + bucket_start[tid] : 0;
        cur[tid] = 0;
    }
    __syncthreads();
    const int base = blockIdx.x * ECHUNK;
    const int end  = min(base + ECHUNK, E);
    const int nvec = (end - base) >> 2;
    const int4* s4p = reinterpret_cast<const int4*>(src + base);
    const int4* d4p = reinterpret_cast<const int4*>(dst + base);
    const int4* t4p = reinterpret_cast<const int4*>(types + base);
    for (int g = tid; g < nvec; g += 1024) {
        int4 sv = s4p[g], dv = d4p[g], tv = t4p[g];
        int b, r;
        // src(0..16) | type(17..22) | dstLow(23..31) - sign bit ok, masked on use
        b = dv.x >> DSHIFT; r = atomicAdd(&cur[b], 1);
        bucketed[lbase[b] + r] = sv.x | (tv.x << 17) | ((dv.x & (DPB - 1)) << 23);
        b = dv.y >> DSHIFT; r = atomicAdd(&cur[b], 1);
        bucketed[lbase[b] + r] = sv.y | (tv.y << 17) | ((dv.y & (DPB - 1)) << 23);
        b = dv.z >> DSHIFT; r = atomicAdd(&cur[b], 1);
        bucketed[lbase[b] + r] = sv.z | (tv.z << 17) | ((dv.z & (DPB - 1)) << 23);
        b = dv.w >> DSHIFT; r = atomicAdd(&cur[b], 1);
        bucketed[lbase[b] + r] = sv.w | (tv.w << 17) | ((dv.w & (DPB - 1)) << 23);
    }
    for (int i = base + (nvec << 2) + tid; i < end; i += 1024) {
        int d = dst[i];
        int b = d >> DSHIFT;
        int r = atomicAdd(&cur[b], 1);
        bucketed[lbase[b] + r] = src[i] | (types[i] << 17) | ((d & (DPB - 1)) << 23);
    }
}

// 1024 threads; scan section runs on first DPB=512 threads.
__global__ __launch_bounds__(1024) void bucket_to_csr_kernel(
    const int* __restrict__ bucket_start, const int* __restrict__ bucket_size,
    const int* __restrict__ bucketed, int* __restrict__ sorted,
    int* __restrict__ row_start, int* __restrict__ deg, int N)
{
    __shared__ int cnt[DPB];
    __shared__ int sc[DPB];
    __shared__ int rs[DPB];
    __shared__ int cur[DPB];
    const int tid = threadIdx.x;
    const int b   = blockIdx.x;
    const int d0  = b << DSHIFT;
    const int nd  = min(DPB, N - d0);
    const int s0  = bucket_start[b];
    const int ne  = bucket_size[b];

    if (tid < DPB) { cnt[tid] = 0; cur[tid] = 0; }
    __syncthreads();
    for (int i = tid; i < ne; i += 1024)
        atomicAdd(&cnt[((unsigned)bucketed[s0 + i] >> 23) & (DPB - 1)], 1);
    __syncthreads();
    int v = 0;
    if (tid < DPB) { v = cnt[tid]; sc[tid] = v; }
    __syncthreads();
    for (int off = 1; off < DPB; off <<= 1) {
        int u = (tid < DPB && tid >= off) ? sc[tid - off] : 0;
        __syncthreads();
        if (tid < DPB) sc[tid] += u;
        __syncthreads();
    }
    if (tid < DPB) {
        int ex = sc[tid] - v;
        rs[tid] = s0 + ex;
        if (tid < nd) {
            row_start[d0 + tid] = s0 + ex;
            deg[d0 + tid] = v;
        }
    }
    __syncthreads();
    for (int i = tid; i < ne; i += 1024) {
        int pk = bucketed[s0 + i];
        int d  = ((unsigned)pk >> 23) & (DPB - 1);
        int r  = atomicAdd(&cur[d], 1);
        sorted[rs[d] + r] = pk & 0x7FFFFF;   // src | type<<17
    }
}

// ---------------- per-layer aggregation ----------------
template <int MODE>
__global__ __launch_bounds__(256) void agg_kernel(
    const int* __restrict__ row_start, const int* __restrict__ deg,
    const int* __restrict__ sorted, const float* __restrict__ wt_l,
    const float* __restrict__ hin, float* __restrict__ hout,
    const float* __restrict__ centrality, const float* __restrict__ gamma,
    const float* __restrict__ beta, int N)
{
    __shared__ float wt[RELNUM * NHEAD];
    for (int i = threadIdx.x; i < RELNUM * NHEAD; i += blockDim.x) wt[i] = wt_l[i];
    __syncthreads();

    int gid = blockIdx.x * blockDim.x + threadIdx.x;
    int d = gid >> 2, h = gid & 3;
    if (d >= N) return;

    int b = row_start[d], n = deg[d];
    float num = 0.f, den = 0.f;
    for (int i = 0; i < n; i++) {
        int pk = sorted[b + i];                 // same addr across the quad
        int s = pk & 0x1FFFF;
        int t = pk >> 17;
        float wv = wt[t * NHEAD + h];
        float hv = (MODE == 0) ? hin[(size_t)s * NHEAD + h] : hin[s];
        num = fmaf(wv, hv, num);
        den += wv;
    }
    float r = (n > 0) ? fmaxf(num / den, 0.f) : 0.f;   // relu(segsum(a*h))
    if (MODE == 2) r = (centrality[d] * gamma[h] + beta[h]) * r;
    r += __shfl_xor(r, 1);
    r += __shfl_xor(r, 2);
    r *= 0.25f;
    if (h == 0) {
        if (MODE < 2) hout[d] = r;
        else          hout[d] = (r > 0.f) ? r : 0.01f * r;
    }
}

// ---------------- launch ----------------
extern "C" void kernel_launch(void* const* d_in, const int* in_sizes, int n_in,
                              void* d_out, int out_size, void* d_ws, size_t ws_size,
                              hipStream_t stream)
{
    const float* X          = (const float*)d_in[0];
    const float* centrality = (const float*)d_in[1];
    const float* W1         = (const float*)d_in[2];
    const float* b1         = (const float*)d_in[3];
    const float* W2         = (const float*)d_in[4];
    const float* b2         = (const float*)d_in[5];
    const float* rel_emb    = (const float*)d_in[6];
    const float* W_pred     = (const float*)d_in[7];
    const float* gamma      = (const float*)d_in[8];
    const float* beta       = (const float*)d_in[9];
    const int*   edge_types = (const int*)d_in[10];
    const int*   src        = (const int*)d_in[11];
    const int*   dst        = (const int*)d_in[12];
    float* out = (float*)d_out;

    const int N = in_sizes[1];
    const int E = in_sizes[10];
    const int nbuck = (N + DPB - 1) / DPB;
    const int eb = (E + ECHUNK - 1) / ECHUNK;

    char* ws = (char*)d_ws;
    size_t off = 0;
    auto alloc = [&](size_t bytes) -> void* {
        void* p = ws + off;
        off = (off + bytes + 255) & ~(size_t)255;
        return p;
    };
    int*   deg       = (int*)alloc((size_t)N * 4);
    int*   row_start = (int*)alloc((size_t)N * 4);
    int*   bsize     = (int*)alloc((size_t)MAXBUCK * 4);
    int*   bstart    = (int*)alloc((size_t)MAXBUCK * 4);
    int*   blockhist = (int*)alloc((size_t)nbuck * eb * 4);
    int*   blockbase = (int*)alloc((size_t)nbuck * eb * 4);
    int*   bucketed  = (int*)alloc((size_t)E * 4);
    int*   sorted    = (int*)alloc((size_t)E * 4);
    float* wtab      = (float*)alloc((size_t)NLAYER * RELNUM * NHEAD * 4);
    float* h0        = (float*)alloc((size_t)N * NHEAD * 4);
    float* hs        = (float*)alloc((size_t)N * 4);
    float* hs2       = (float*)alloc((size_t)N * 4);
    _Float16* Wh     = (_Float16*)alloc((size_t)NCOL * INDIM * 2);
    _Float16* Wl     = (_Float16*)alloc((size_t)NCOL * INDIM * 2);
    (void)ws_size; (void)n_in; (void)out_size;

    bucket_count_kernel<<<eb, 1024, 0, stream>>>(dst, blockhist, E, nbuck, eb);
    scan_chunks_kernel<<<nbuck, MAXCHUNK, 0, stream>>>(blockhist, blockbase, bsize, eb);
    scan_buckets_kernel<<<1, 256, 0, stream>>>(bsize, bstart, nbuck);
    bucket_scatter_kernel<<<eb, 1024, 0, stream>>>(src, dst, edge_types, blockbase,
                                                   bstart, bucketed, E, nbuck, eb);
    bucket_to_csr_kernel<<<nbuck, 1024, 0, stream>>>(bstart, bsize, bucketed, sorted,
                                                     row_start, deg, N);

    table_kernel<<<(NLAYER * RELNUM * NHEAD + 255) / 256, 256, 0, stream>>>(rel_emb, W_pred, wtab);
    split_w1<<<(NCOL * INDIM) / 256, 256, 0, stream>>>(W1, Wh, Wl);
    mlp_mfma_kernel<<<(N + MLP_NODES - 1) / MLP_NODES, 256, 0, stream>>>(
        X, Wh, Wl, b1, W2, b2, h0, N);

    const int ab = (N * NHEAD + 255) / 256;
    agg_kernel<0><<<ab, 256, 0, stream>>>(row_start, deg, sorted, wtab + 0 * RELNUM * NHEAD,
                                          h0, hs, nullptr, nullptr, nullptr, N);
    agg_kernel<1><<<ab, 256, 0, stream>>>(row_start, deg, sorted, wtab + 1 * RELNUM * NHEAD,
                                          hs, hs2, nullptr, nullptr, nullptr, N);
    agg_kernel<2><<<ab, 256, 0, stream>>>(row_start, deg, sorted, wtab + 2 * RELNUM * NHEAD,
                                          hs2, out, centrality, gamma, beta, N);
}

// Round 12
// 288.717 us; speedup vs baseline: 1.4562x; 1.0215x over previous
//
#include <hip/hip_runtime.h>
#include <cstdint>
#include <cstddef>

#define NHEAD 4
#define HID 64
#define NCOL 256          // NHEAD*HID
#define INDIM 128
#define PREDDIM 16
#define RELNUM 50
#define NLAYER 3
#define ECHUNK 8192       // edges per chunk-block in bucket build
#define DSHIFT 9          // 512 dsts per bucket
#define DPB 512           // dsts per bucket (src17+type6+dstLow9 = 32 bits)
#define MAXBUCK 256       // >= ceil(N/DPB)=196; LDS hist size
#define MAXCHUNK 512      // >= ceil(E/ECHUNK)=391
#define MLP_NODES 64      // nodes per block in MFMA MLP

typedef _Float16 half8 __attribute__((ext_vector_type(8)));
typedef float float4v __attribute__((ext_vector_type(4)));

// ---------------- W1 hi/lo f16 split (once) ----------------
// fp32 = hi + lo/2048 exactly to ~2^-22 rel; lo scaled x2048 so W~0.05
// residuals stay in f16 normal range (avoids denorm-flush error).
__global__ void split_w1(const float* __restrict__ W1,
                         _Float16* __restrict__ Wh, _Float16* __restrict__ Wl)
{
    int i = blockIdx.x * 256 + threadIdx.x;    // NCOL*INDIM = 32768 total
    float v = W1[i];
    _Float16 h = (_Float16)v;
    Wh[i] = h;
    Wl[i] = (_Float16)((v - (float)h) * 2048.0f);
}

// ---------------- node scoring MLP via split-f16 MFMA ----------------
// Round-11: MfmaUtil 12.7% -> 88% overhead, dominated by LDS pipe (128
// ds_read_b128/wave: A-frags re-read every ct) + 8-way-conflicted staging
// writes (ks stride 1024B = same banks; 1.2M SQ_LDS_BANK_CONFLICT).
// Fix: (a) hoist all 32 A-frags into registers before the ct loop (LDS
// reads /4); (b) XOR slot swizzle ^(2*ks) kills the write conflicts.
// Round-7 lesson stands: ct loop stays '#pragma unroll 1' (full unroll
// spilled 150 MB). Fragment conventions (verified rounds 5-11 passing):
// A[m=lane&15][k=(lane>>4)*8+j], D col=lane&15, row=(lane>>4)*4+reg.
__global__ __launch_bounds__(256, 2) void mlp_mfma_kernel(
    const float* __restrict__ X, const _Float16* __restrict__ Wh,
    const _Float16* __restrict__ Wl, const float* __restrict__ b1,
    const float* __restrict__ W2, const float* __restrict__ b2,
    float* __restrict__ h0, int N)
{
    __shared__ _Float16 hA[4][4][64][8];   // [mt][ks][slot][j], 16 KB
    __shared__ _Float16 lA[4][4][64][8];

    const int tid = threadIdx.x;
    const int n0  = blockIdx.x * MLP_NODES;

    // ---- stage: thread = (node mg=tid>>2, ks=tid&3): 32 floats -> hi/lo ----
    {
        const int mg = tid >> 2, ks = tid & 3;
        const int gn = min(n0 + mg, N - 1);     // clamp; stores guarded later
        const float4* Xp = reinterpret_cast<const float4*>(X + (size_t)gn * INDIM + ks * 32);
        const int mt = mg >> 4, m = mg & 15;
        #pragma unroll
        for (int q = 0; q < 4; q++) {
            float4 x0 = Xp[q * 2], x1 = Xp[q * 2 + 1];
            float xs[8] = { x0.x,x0.y,x0.z,x0.w, x1.x,x1.y,x1.z,x1.w };
            half8 hv, lv;
            #pragma unroll
            for (int j = 0; j < 8; j++) {
                _Float16 hh = (_Float16)xs[j];
                hv[j] = hh;
                lv[j] = (_Float16)((xs[j] - (float)hh) * 2048.0f);
            }
            const int slot = (q * 16 + m) ^ (2 * ks);   // bank-spread swizzle
            *reinterpret_cast<half8*>(&hA[mt][ks][slot][0]) = hv;
            *reinterpret_cast<half8*>(&lA[mt][ks][slot][0]) = lv;
        }
    }
    __syncthreads();

    const int w    = tid >> 6;             // wave = head
    const int lane = tid & 63;
    const int n16  = lane & 15;
    const int q    = lane >> 4;

    // ---- A-frags into registers ONCE (32 half8 = 128 VGPR) ----
    half8 ahr[4][4], alr[4][4];
    #pragma unroll
    for (int mt = 0; mt < 4; mt++)
        #pragma unroll
        for (int ks = 0; ks < 4; ks++) {
            const int slot = lane ^ (2 * ks);
            ahr[mt][ks] = *reinterpret_cast<const half8*>(&hA[mt][ks][slot][0]);
            alr[mt][ks] = *reinterpret_cast<const half8*>(&lA[mt][ks][slot][0]);
        }

    float s[4][4];                         // [mt][reg] per-head partials
    #pragma unroll
    for (int mt = 0; mt < 4; mt++)
        #pragma unroll
        for (int r = 0; r < 4; r++) s[mt][r] = 0.f;

    #pragma unroll 1                       // DO NOT unroll: keeps one ct's
    for (int ct = 0; ct < 4; ct++) {       // B-frags (32 VGPR) live, not 128
        const int c = w * 64 + ct * 16 + n16;
        const _Float16* pb = Wh + (size_t)c * INDIM + q * 8;
        const _Float16* pl = Wl + (size_t)c * INDIM + q * 8;
        half8 bh[4], bl[4];
        #pragma unroll
        for (int ks = 0; ks < 4; ks++) {
            bh[ks] = *reinterpret_cast<const half8*>(pb + ks * 32);
            bl[ks] = *reinterpret_cast<const half8*>(pl + ks * 32);
        }
        const float b1v = b1[c];
        const float w2v = W2[c];

        #pragma unroll
        for (int mt = 0; mt < 4; mt++) {
            float4v acc = (float4v){0.f,0.f,0.f,0.f};
            float4v aca = (float4v){0.f,0.f,0.f,0.f};
            float4v acb = (float4v){0.f,0.f,0.f,0.f};
            #pragma unroll
            for (int ks = 0; ks < 4; ks++) {
                acc = __builtin_amdgcn_mfma_f32_16x16x32_f16(ahr[mt][ks], bh[ks], acc, 0, 0, 0);
                aca = __builtin_amdgcn_mfma_f32_16x16x32_f16(ahr[mt][ks], bl[ks], aca, 0, 0, 0);
                acb = __builtin_amdgcn_mfma_f32_16x16x32_f16(alr[mt][ks], bh[ks], acb, 0, 0, 0);
            }
            #pragma unroll
            for (int r = 0; r < 4; r++) {
                float v = acc[r] + (aca[r] + acb[r]) * (1.0f / 2048.0f) + b1v;
                s[mt][r] += fmaxf(v, 0.f) * w2v;
            }
        }
    }

    // ---- reduce over n16 (16 lanes = 16 cols of this head) + store ----
    const float bk = b2[w];
    #pragma unroll
    for (int mt = 0; mt < 4; mt++) {
        #pragma unroll
        for (int r = 0; r < 4; r++) {
            float v = s[mt][r];
            v += __shfl_down(v, 8, 16);
            v += __shfl_down(v, 4, 16);
            v += __shfl_down(v, 2, 16);
            v += __shfl_down(v, 1, 16);
            if (n16 == 0) {
                int node = n0 + mt * 16 + q * 4 + r;
                if (node < N) h0[(size_t)node * NHEAD + w] = v + bk;
            }
        }
    }
}

// ---------------- attention weight table ----------------
__global__ void table_kernel(const float* __restrict__ rel_emb,
                             const float* __restrict__ W_pred,
                             float* __restrict__ wtab)
{
    int idx = blockIdx.x * blockDim.x + threadIdx.x;
    if (idx >= NLAYER * RELNUM * NHEAD) return;
    int h = idx & 3;
    int q = idx >> 2;
    int t = q % RELNUM;
    int l = q / RELNUM;
    float acc = 0.f;
    #pragma unroll
    for (int p = 0; p < PREDDIM; p++)
        acc = fmaf(rel_emb[t * PREDDIM + p], W_pred[l * PREDDIM * NHEAD + p * NHEAD + h], acc);
    float e = (acc >= 0.f) ? acc : 0.2f * acc;
    wtab[idx] = __expf(e);
}

// ---------------- bucketed CSR build ----------------
// blockhist/blockbase are BUCKET-MAJOR: [bucket][chunk].
__global__ __launch_bounds__(1024) void bucket_count_kernel(
    const int* __restrict__ dst, int* __restrict__ blockhist, int E,
    int nbuck, int nb)
{
    __shared__ int hist[MAXBUCK];
    const int tid = threadIdx.x;
    if (tid < MAXBUCK) hist[tid] = 0;
    __syncthreads();
    const int base = blockIdx.x * ECHUNK;
    const int end  = min(base + ECHUNK, E);
    const int nvec = (end - base) >> 2;
    const int4* d4p = reinterpret_cast<const int4*>(dst + base);
    for (int g = tid; g < nvec; g += 1024) {
        int4 d = d4p[g];
        atomicAdd(&hist[d.x >> DSHIFT], 1);
        atomicAdd(&hist[d.y >> DSHIFT], 1);
        atomicAdd(&hist[d.z >> DSHIFT], 1);
        atomicAdd(&hist[d.w >> DSHIFT], 1);
    }
    for (int i = base + (nvec << 2) + tid; i < end; i += 1024)
        atomicAdd(&hist[dst[i] >> DSHIFT], 1);
    __syncthreads();
    if (tid < nbuck) blockhist[(size_t)tid * nb + blockIdx.x] = hist[tid];
}

// one block per bucket: exclusive scan over its nb chunk counts (nb<=512)
__global__ __launch_bounds__(512) void scan_chunks_kernel(
    const int* __restrict__ blockhist, int* __restrict__ blockbase,
    int* __restrict__ bucket_size, int nb)
{
    __shared__ int s[MAXCHUNK];
    const int b = blockIdx.x;
    const int t = threadIdx.x;
    int v = (t < nb) ? blockhist[(size_t)b * nb + t] : 0;
    s[t] = v;
    __syncthreads();
    for (int off = 1; off < MAXCHUNK; off <<= 1) {
        int u = (t >= off) ? s[t - off] : 0;
        __syncthreads();
        s[t] += u;
        __syncthreads();
    }
    if (t < nb) blockbase[(size_t)b * nb + t] = s[t] - v;   // excl. within bucket
    if (t == MAXCHUNK - 1) bucket_size[b] = s[t];
}

// one small block: exclusive scan of bucket sizes (nbuck <= 256)
__global__ __launch_bounds__(256) void scan_buckets_kernel(
    const int* __restrict__ bucket_size, int* __restrict__ bucket_start, int nbuck)
{
    __shared__ int s[256];
    const int t = threadIdx.x;
    int v = (t < nbuck) ? bucket_size[t] : 0;
    s[t] = v;
    __syncthreads();
    for (int off = 1; off < 256; off <<= 1) {
        int u = (t >= off) ? s[t - off] : 0;
        __syncthreads();
        s[t] += u;
        __syncthreads();
    }
    if (t < nbuck) bucket_start[t] = s[t] - v;
}

__global__ __launch_bounds__(1024) void bucket_scatter_kernel(
    const int* __restrict__ src, const int* __restrict__ dst,
    const int* __restrict__ types, const int* __restrict__ blockbase,
    const int* __restrict__ bucket_start, int* __restrict__ bucketed,
    int E, int nbuck, int nb)
{
    __shared__ int lbase[MAXBUCK];
    __shared__ int cur[MAXBUCK];
    const int tid = threadIdx.x;
    if (tid < MAXBUCK) {
        lbase[tid] = (tid < nbuck)
            ? blockbase[(size_t)tid * nb + blockIdx.x] + bucket_start[tid] : 0;
        cur[tid] = 0;
    }
    __syncthreads();
    const int base = blockIdx.x * ECHUNK;
    const int end  = min(base + ECHUNK, E);
    const int nvec = (end - base) >> 2;
    const int4* s4p = reinterpret_cast<const int4*>(src + base);
    const int4* d4p = reinterpret_cast<const int4*>(dst + base);
    const int4* t4p = reinterpret_cast<const int4*>(types + base);
    for (int g = tid; g < nvec; g += 1024) {
        int4 sv = s4p[g], dv = d4p[g], tv = t4p[g];
        int b, r;
        // src(0..16) | type(17..22) | dstLow(23..31) - sign bit ok, masked on use
        b = dv.x >> DSHIFT; r = atomicAdd(&cur[b], 1);
        bucketed[lbase[b] + r] = sv.x | (tv.x << 17) | ((dv.x & (DPB - 1)) << 23);
        b = dv.y >> DSHIFT; r = atomicAdd(&cur[b], 1);
        bucketed[lbase[b] + r] = sv.y | (tv.y << 17) | ((dv.y & (DPB - 1)) << 23);
        b = dv.z >> DSHIFT; r = atomicAdd(&cur[b], 1);
        bucketed[lbase[b] + r] = sv.z | (tv.z << 17) | ((dv.z & (DPB - 1)) << 23);
        b = dv.w >> DSHIFT; r = atomicAdd(&cur[b], 1);
        bucketed[lbase[b] + r] = sv.w | (tv.w << 17) | ((dv.w & (DPB - 1)) << 23);
    }
    for (int i = base + (nvec << 2) + tid; i < end; i += 1024) {
        int d = dst[i];
        int b = d >> DSHIFT;
        int r = atomicAdd(&cur[b], 1);
        bucketed[lbase[b] + r] = src[i] | (types[i] << 17) | ((d & (DPB - 1)) << 23);
    }
}

// 1024 threads; scan section runs on first DPB=512 threads.
__global__ __launch_bounds__(1024) void bucket_to_csr_kernel(
    const int* __restrict__ bucket_start, const int* __restrict__ bucket_size,
    const int* __restrict__ bucketed, int* __restrict__ sorted,
    int* __restrict__ row_start, int* __restrict__ deg, int N)
{
    __shared__ int cnt[DPB];
    __shared__ int sc[DPB];
    __shared__ int rs[DPB];
    __shared__ int cur[DPB];
    const int tid = threadIdx.x;
    const int b   = blockIdx.x;
    const int d0  = b << DSHIFT;
    const int nd  = min(DPB, N - d0);
    const int s0  = bucket_start[b];
    const int ne  = bucket_size[b];

    if (tid < DPB) { cnt[tid] = 0; cur[tid] = 0; }
    __syncthreads();
    for (int i = tid; i < ne; i += 1024)
        atomicAdd(&cnt[((unsigned)bucketed[s0 + i] >> 23) & (DPB - 1)], 1);
    __syncthreads();
    int v = 0;
    if (tid < DPB) { v = cnt[tid]; sc[tid] = v; }
    __syncthreads();
    for (int off = 1; off < DPB; off <<= 1) {
        int u = (tid < DPB && tid >= off) ? sc[tid - off] : 0;
        __syncthreads();
        if (tid < DPB) sc[tid] += u;
        __syncthreads();
    }
    if (tid < DPB) {
        int ex = sc[tid] - v;
        rs[tid] = s0 + ex;
        if (tid < nd) {
            row_start[d0 + tid] = s0 + ex;
            deg[d0 + tid] = v;
        }
    }
    __syncthreads();
    for (int i = tid; i < ne; i += 1024) {
        int pk = bucketed[s0 + i];
        int d  = ((unsigned)pk >> 23) & (DPB - 1);
        int r  = atomicAdd(&cur[d], 1);
        sorted[rs[d] + r] = pk & 0x7FFFFF;   // src | type<<17
    }
}

// ---------------- per-layer aggregation ----------------
template <int MODE>
__global__ __launch_bounds__(256) void agg_kernel(
    const int* __restrict__ row_start, const int* __restrict__ deg,
    const int* __restrict__ sorted, const float* __restrict__ wt_l,
    const float* __restrict__ hin, float* __restrict__ hout,
    const float* __restrict__ centrality, const float* __restrict__ gamma,
    const float* __restrict__ beta, int N)
{
    __shared__ float wt[RELNUM * NHEAD];
    for (int i = threadIdx.x; i < RELNUM * NHEAD; i += blockDim.x) wt[i] = wt_l[i];
    __syncthreads();

    int gid = blockIdx.x * blockDim.x + threadIdx.x;
    int d = gid >> 2, h = gid & 3;
    if (d >= N) return;

    int b = row_start[d], n = deg[d];
    float num = 0.f, den = 0.f;
    for (int i = 0; i < n; i++) {
        int pk = sorted[b + i];                 // same addr across the quad
        int s = pk & 0x1FFFF;
        int t = pk >> 17;
        float wv = wt[t * NHEAD + h];
        float hv = (MODE == 0) ? hin[(size_t)s * NHEAD + h] : hin[s];
        num = fmaf(wv, hv, num);
        den += wv;
    }
    float r = (n > 0) ? fmaxf(num / den, 0.f) : 0.f;   // relu(segsum(a*h))
    if (MODE == 2) r = (centrality[d] * gamma[h] + beta[h]) * r;
    r += __shfl_xor(r, 1);
    r += __shfl_xor(r, 2);
    r *= 0.25f;
    if (h == 0) {
        if (MODE < 2) hout[d] = r;
        else          hout[d] = (r > 0.f) ? r : 0.01f * r;
    }
}

// ---------------- launch ----------------
extern "C" void kernel_launch(void* const* d_in, const int* in_sizes, int n_in,
                              void* d_out, int out_size, void* d_ws, size_t ws_size,
                              hipStream_t stream)
{
    const float* X          = (const float*)d_in[0];
    const float* centrality = (const float*)d_in[1];
    const float* W1         = (const float*)d_in[2];
    const float* b1         = (const float*)d_in[3];
    const float* W2         = (const float*)d_in[4];
    const float* b2         = (const float*)d_in[5];
    const float* rel_emb    = (const float*)d_in[6];
    const float* W_pred     = (const float*)d_in[7];
    const float* gamma      = (const float*)d_in[8];
    const float* beta       = (const float*)d_in[9];
    const int*   edge_types = (const int*)d_in[10];
    const int*   src        = (const int*)d_in[11];
    const int*   dst        = (const int*)d_in[12];
    float* out = (float*)d_out;

    const int N = in_sizes[1];
    const int E = in_sizes[10];
    const int nbuck = (N + DPB - 1) / DPB;
    const int eb = (E + ECHUNK - 1) / ECHUNK;

    char* ws = (char*)d_ws;
    size_t off = 0;
    auto alloc = [&](size_t bytes) -> void* {
        void* p = ws + off;
        off = (off + bytes + 255) & ~(size_t)255;
        return p;
    };
    int*   deg       = (int*)alloc((size_t)N * 4);
    int*   row_start = (int*)alloc((size_t)N * 4);
    int*   bsize     = (int*)alloc((size_t)MAXBUCK * 4);
    int*   bstart    = (int*)alloc((size_t)MAXBUCK * 4);
    int*   blockhist = (int*)alloc((size_t)nbuck * eb * 4);
    int*   blockbase = (int*)alloc((size_t)nbuck * eb * 4);
    int*   bucketed  = (int*)alloc((size_t)E * 4);
    int*   sorted    = (int*)alloc((size_t)E * 4);
    float* wtab      = (float*)alloc((size_t)NLAYER * RELNUM * NHEAD * 4);
    float* h0        = (float*)alloc((size_t)N * NHEAD * 4);
    float* hs        = (float*)alloc((size_t)N * 4);
    float* hs2       = (float*)alloc((size_t)N * 4);
    _Float16* Wh     = (_Float16*)alloc((size_t)NCOL * INDIM * 2);
    _Float16* Wl     = (_Float16*)alloc((size_t)NCOL * INDIM * 2);
    (void)ws_size; (void)n_in; (void)out_size;

    bucket_count_kernel<<<eb, 1024, 0, stream>>>(dst, blockhist, E, nbuck, eb);
    scan_chunks_kernel<<<nbuck, MAXCHUNK, 0, stream>>>(blockhist, blockbase, bsize, eb);
    scan_buckets_kernel<<<1, 256, 0, stream>>>(bsize, bstart, nbuck);
    bucket_scatter_kernel<<<eb, 1024, 0, stream>>>(src, dst, edge_types, blockbase,
                                                   bstart, bucketed, E, nbuck, eb);
    bucket_to_csr_kernel<<<nbuck, 1024, 0, stream>>>(bstart, bsize, bucketed, sorted,
                                                     row_start, deg, N);

    table_kernel<<<(NLAYER * RELNUM * NHEAD + 255) / 256, 256, 0, stream>>>(rel_emb, W_pred, wtab);
    split_w1<<<(NCOL * INDIM) / 256, 256, 0, stream>>>(W1, Wh, Wl);
    mlp_mfma_kernel<<<(N + MLP_NODES - 1) / MLP_NODES, 256, 0, stream>>>(
        X, Wh, Wl, b1, W2, b2, h0, N);

    const int ab = (N * NHEAD + 255) / 256;
    agg_kernel<0><<<ab, 256, 0, stream>>>(row_start, deg, sorted, wtab + 0 * RELNUM * NHEAD,
                                          h0, hs, nullptr, nullptr, nullptr, N);
    agg_kernel<1><<<ab, 256, 0, stream>>>(row_start, deg, sorted, wtab + 1 * RELNUM * NHEAD,
                                          hs, hs2, nullptr, nullptr, nullptr, N);
    agg_kernel<2><<<ab, 256, 0, stream>>>(row_start, deg, sorted, wtab + 2 * RELNUM * NHEAD,
                                          hs2, out, centrality, gamma, beta, N);
}